// Round 1
// baseline (109.568 us; speedup 1.0000x reference)
//
#include <hip/hip_runtime.h>
#include <math.h>

// Fused fuzzy LeNet-5 (Yager p=1 == Lukasiewicz: T(a,b)=max(0, a+b-1)).
// Fuzzy conv == max-plus conv: out = max(0, max_{c,kh,kw}(x + w) - 1).
// One block per batch image; all activations in LDS; single kernel launch.

#define NTHREADS 256

__global__ __launch_bounds__(NTHREADS) void fuzzy_lenet_kernel(
    const float* __restrict__ x_in,   // [B,3,32,32]
    const float* __restrict__ w1,     // [6,3,5,5]
    const float* __restrict__ w2,     // [16,6,5,5]
    const float* __restrict__ w3,     // [120,16,5,5]
    const float* __restrict__ wd,     // [120,84]
    const float* __restrict__ wf,     // [84,10]
    const float* __restrict__ bfv,    // [10]
    float* __restrict__ out)          // [B,10]
{
    const int b = blockIdx.x;
    const int tid = threadIdx.x;

    __shared__ float s_in[3 * 32 * 32];   // 12 KB
    __shared__ float s_w1[6 * 3 * 5 * 5];
    __shared__ float s_w2[16 * 6 * 5 * 5];
    __shared__ float s_a1[6 * 14 * 14];   // pooled L1
    __shared__ float s_a2[16 * 5 * 5];    // pooled L2
    __shared__ float s_a3[120];
    __shared__ float s_a4[84];
    __shared__ float s_logits[10];
    __shared__ float s_red[2];

    // ---- stage inputs & small weights to LDS
    const float* xb = x_in + b * 3072;
    for (int i = tid; i < 3072; i += NTHREADS) s_in[i] = xb[i];
    for (int i = tid; i < 450; i += NTHREADS)  s_w1[i] = w1[i];
    for (int i = tid; i < 2400; i += NTHREADS) s_w2[i] = w2[i];
    __syncthreads();

    // ---- Layer 1 + 2x2 maxpool: [3,32,32] -> [6,14,14]
    for (int idx = tid; idx < 6 * 14 * 14; idx += NTHREADS) {
        const int o = idx / 196;
        const int rem = idx - o * 196;
        const int py = rem / 14;
        const int px = rem - py * 14;
        const float* wo = s_w1 + o * 75;
        float m = -1e30f;
        #pragma unroll
        for (int dy = 0; dy < 2; ++dy) {
            #pragma unroll
            for (int dx = 0; dx < 2; ++dx) {
                const int hy = 2 * py + dy;
                const int hx = 2 * px + dx;
                for (int c = 0; c < 3; ++c) {
                    const float* xc = s_in + c * 1024 + hy * 32 + hx;
                    const float* wc = wo + c * 25;
                    #pragma unroll
                    for (int kh = 0; kh < 5; ++kh) {
                        #pragma unroll
                        for (int kw = 0; kw < 5; ++kw)
                            m = fmaxf(m, xc[kh * 32 + kw] + wc[kh * 5 + kw]);
                    }
                }
            }
        }
        s_a1[idx] = fmaxf(m - 1.0f, 0.0f);
    }
    __syncthreads();

    // ---- Layer 2 + 2x2 maxpool: [6,14,14] -> [16,5,5]
    for (int idx = tid; idx < 16 * 5 * 5; idx += NTHREADS) {
        const int o = idx / 25;
        const int rem = idx - o * 25;
        const int py = rem / 5;
        const int px = rem - py * 5;
        const float* wo = s_w2 + o * 150;
        float m = -1e30f;
        #pragma unroll
        for (int dy = 0; dy < 2; ++dy) {
            #pragma unroll
            for (int dx = 0; dx < 2; ++dx) {
                const int hy = 2 * py + dy;
                const int hx = 2 * px + dx;
                for (int c = 0; c < 6; ++c) {
                    const float* xc = s_a1 + c * 196 + hy * 14 + hx;
                    const float* wc = wo + c * 25;
                    #pragma unroll
                    for (int kh = 0; kh < 5; ++kh) {
                        #pragma unroll
                        for (int kw = 0; kw < 5; ++kw)
                            m = fmaxf(m, xc[kh * 14 + kw] + wc[kh * 5 + kw]);
                    }
                }
            }
        }
        s_a2[idx] = fmaxf(m - 1.0f, 0.0f);
    }
    __syncthreads();

    // ---- Layer 3: [16,5,5] -> [120]  (w3 from global, float4 reads, L2-resident)
    if (tid < 120) {
        const float4* wo = reinterpret_cast<const float4*>(w3 + tid * 400);
        const float4* av = reinterpret_cast<const float4*>(s_a2);
        float m = -1e30f;
        for (int l = 0; l < 100; ++l) {
            float4 w = wo[l];
            float4 a = av[l];
            m = fmaxf(m, fmaxf(fmaxf(a.x + w.x, a.y + w.y),
                               fmaxf(a.z + w.z, a.w + w.w)));
        }
        s_a3[tid] = fmaxf(m - 1.0f, 0.0f);
    }
    __syncthreads();

    // ---- Dense [120]->[84] + tanh  (wd reads coalesced across threads)
    if (tid < 84) {
        float acc = 0.0f;
        for (int i = 0; i < 120; ++i)
            acc = fmaf(s_a3[i], wd[i * 84 + tid], acc);
        s_a4[tid] = tanhf(acc);
    }
    __syncthreads();

    // ---- FC [84]->[10] + bias
    if (tid < 10) {
        float acc = bfv[tid];
        for (int i = 0; i < 84; ++i)
            acc = fmaf(s_a4[i], wf[i * 10 + tid], acc);
        s_logits[tid] = acc;
    }
    __syncthreads();

    // ---- log_softmax over 10 classes
    if (tid == 0) {
        float m = s_logits[0];
        for (int i = 1; i < 10; ++i) m = fmaxf(m, s_logits[i]);
        float s = 0.0f;
        for (int i = 0; i < 10; ++i) s += expf(s_logits[i] - m);
        s_red[0] = m;
        s_red[1] = logf(s);
    }
    __syncthreads();
    if (tid < 10)
        out[b * 10 + tid] = s_logits[tid] - s_red[0] - s_red[1];
}

extern "C" void kernel_launch(void* const* d_in, const int* in_sizes, int n_in,
                              void* d_out, int out_size, void* d_ws, size_t ws_size,
                              hipStream_t stream) {
    const float* x   = (const float*)d_in[0];
    const float* w1  = (const float*)d_in[1];
    const float* w2  = (const float*)d_in[2];
    const float* w3  = (const float*)d_in[3];
    const float* wd  = (const float*)d_in[4];
    const float* wf  = (const float*)d_in[5];
    const float* bfv = (const float*)d_in[6];
    float* out = (float*)d_out;

    const int B = in_sizes[0] / (3 * 32 * 32);
    fuzzy_lenet_kernel<<<dim3(B), dim3(NTHREADS), 0, stream>>>(
        x, w1, w2, w3, wd, wf, bfv, out);
}

// Round 2
// 97.039 us; speedup vs baseline: 1.1291x; 1.1291x over previous
//
#include <hip/hip_runtime.h>
#include <math.h>

// Fuzzy LeNet-5, Yager p=1 == Lukasiewicz t-norm: T(a,b) = max(0, a+b-1).
// Fuzzy conv == max-plus conv: out = relu(max_{c,kh,kw}(x + w) - 1).
// relu is monotone => maxpool2(relu(conv)) = relu(maxpool2(conv) - 1 form),
// and maxpool2 of a max-plus conv folds into a single 6x6 max-plus conv with
// dilated weights W'[uy][ux] = max_{dy,dx in {0,1}, valid} w[uy-dy][ux-dx].
// Three kernels so each layer gets a saturating grid (the single-block-chain
// version was latency-bound at 5% occupancy).

// ---------- Kernel 1: [B,3,32,32] -> [B,6,14,14], grid B*6, block 256 ----------
#define K1_ROWS 34              // padded row stride (floats) to break bank conflicts
#define K1_PLANE (32 * K1_ROWS) // 1088

__global__ __launch_bounds__(256) void k1_conv1(
    const float* __restrict__ x, const float* __restrict__ w1,
    float* __restrict__ a1)
{
    const int bx = blockIdx.x;
    const int img = bx / 6;
    const int oc = bx - img * 6;
    const int tid = threadIdx.x;

    __shared__ float s_in[3 * K1_PLANE];  // 3264 floats, padded rows
    __shared__ float s_w[3 * 36];         // dilated weights [c][uy][ux]

    // stage input image (float2, strided into padded layout)
    const float2* src = (const float2*)(x + img * 3072);
    for (int i = tid; i < 1536; i += 256) {
        const int c = i >> 9;             // /512 float2 per plane
        const int rem = i - (c << 9);
        const int r = rem >> 4;           // /16 float2 per row
        const int col2 = rem & 15;
        ((float2*)s_in)[c * (K1_PLANE / 2) + r * (K1_ROWS / 2) + col2] = src[i];
    }
    // dilated weights for this oc
    if (tid < 108) {
        const int c = tid / 36;
        const int u = tid - c * 36;
        const int r = u / 6, col = u - r * 6;
        const float* wb = w1 + oc * 75 + c * 25;
        float m = -1e30f;
        #pragma unroll
        for (int dy = 0; dy < 2; ++dy) {
            const int kh = r - dy;
            if ((unsigned)kh > 4u) continue;
            #pragma unroll
            for (int dx = 0; dx < 2; ++dx) {
                const int kw = col - dx;
                if ((unsigned)kw > 4u) continue;
                m = fmaxf(m, wb[kh * 5 + kw]);
            }
        }
        s_w[tid] = m;
    }
    __syncthreads();

    if (tid < 196) {
        const int py = tid / 14, px = tid - py * 14;
        float m = -1e30f;
        #pragma unroll
        for (int c = 0; c < 3; ++c) {
            const float* xc = s_in + c * K1_PLANE + 2 * py * K1_ROWS + 2 * px;
            const float* wc = s_w + c * 36;
            #pragma unroll
            for (int uy = 0; uy < 6; ++uy) {
                const float2 x0 = *(const float2*)(xc + uy * K1_ROWS);
                const float2 x1 = *(const float2*)(xc + uy * K1_ROWS + 2);
                const float2 x2 = *(const float2*)(xc + uy * K1_ROWS + 4);
                const float2 w0 = *(const float2*)(wc + uy * 6);
                const float2 w1v = *(const float2*)(wc + uy * 6 + 2);
                const float2 w2v = *(const float2*)(wc + uy * 6 + 4);
                m = fmaxf(m, fmaxf(fmaxf(x0.x + w0.x, x0.y + w0.y),
                          fmaxf(fmaxf(x1.x + w1v.x, x1.y + w1v.y),
                                fmaxf(x2.x + w2v.x, x2.y + w2v.y))));
            }
        }
        a1[img * 1176 + oc * 196 + tid] = fmaxf(m - 1.0f, 0.0f);
    }
}

// ---------- Kernel 2: [B,6,14,14] -> [B,16,5,5], grid B*4, block 128 ----------
__global__ __launch_bounds__(128) void k2_conv2(
    const float* __restrict__ a1, const float* __restrict__ w2,
    float* __restrict__ a2)
{
    const int bx = blockIdx.x;
    const int img = bx >> 2;
    const int g = bx & 3;                 // group of 4 output channels
    const int tid = threadIdx.x;

    __shared__ float s_a1[1176];
    __shared__ float s_w[4 * 216];        // dilated weights [ocl][c][uy][ux]

    const float2* src = (const float2*)(a1 + img * 1176);
    for (int i = tid; i < 588; i += 128) ((float2*)s_a1)[i] = src[i];

    for (int e = tid; e < 864; e += 128) {
        const int ocl = e / 216;
        const int u = e - ocl * 216;
        const int c = u / 36;
        const int v = u - c * 36;
        const int r = v / 6, col = v - r * 6;
        const float* wb = w2 + (g * 4 + ocl) * 150 + c * 25;
        float m = -1e30f;
        #pragma unroll
        for (int dy = 0; dy < 2; ++dy) {
            const int kh = r - dy;
            if ((unsigned)kh > 4u) continue;
            #pragma unroll
            for (int dx = 0; dx < 2; ++dx) {
                const int kw = col - dx;
                if ((unsigned)kw > 4u) continue;
                m = fmaxf(m, wb[kh * 5 + kw]);
            }
        }
        s_w[e] = m;
    }
    __syncthreads();

    if (tid < 100) {
        const int ocl = tid / 25;
        const int pix = tid - ocl * 25;
        const int py = pix / 5, px = pix - py * 5;
        float m = -1e30f;
        #pragma unroll
        for (int c = 0; c < 6; ++c) {
            const float* xc = s_a1 + c * 196 + 2 * py * 14 + 2 * px;
            const float* wc = s_w + ocl * 216 + c * 36;
            #pragma unroll
            for (int uy = 0; uy < 6; ++uy) {
                const float2 x0 = *(const float2*)(xc + uy * 14);
                const float2 x1 = *(const float2*)(xc + uy * 14 + 2);
                const float2 x2 = *(const float2*)(xc + uy * 14 + 4);
                const float2 w0 = *(const float2*)(wc + uy * 6);
                const float2 w1v = *(const float2*)(wc + uy * 6 + 2);
                const float2 w2v = *(const float2*)(wc + uy * 6 + 4);
                m = fmaxf(m, fmaxf(fmaxf(x0.x + w0.x, x0.y + w0.y),
                          fmaxf(fmaxf(x1.x + w1v.x, x1.y + w1v.y),
                                fmaxf(x2.x + w2v.x, x2.y + w2v.y))));
            }
        }
        a2[img * 400 + (g * 4 + ocl) * 25 + pix] = fmaxf(m - 1.0f, 0.0f);
    }
}

// ---------- Kernel 3: L3 + dense/tanh + fc + log_softmax, grid B, block 256 ----------
__global__ __launch_bounds__(256) void k3_head(
    const float* __restrict__ a2, const float* __restrict__ w3,
    const float* __restrict__ wd, const float* __restrict__ wf,
    const float* __restrict__ bfv, float* __restrict__ out)
{
    const int img = blockIdx.x;
    const int tid = threadIdx.x;

    __shared__ float s_a2[400];
    __shared__ float s_a3[120];
    __shared__ float s_a4[84];
    __shared__ float s_logits[10];
    __shared__ float s_red[2];

    const float4* src = (const float4*)(a2 + img * 400);
    for (int i = tid; i < 100; i += 256) ((float4*)s_a2)[i] = src[i];
    __syncthreads();

    // L3: 120 outputs, 2 threads each (200 terms per half), float4 reads of w3
    if (tid < 240) {
        const int o = tid >> 1, h = tid & 1;
        const float4* wv = (const float4*)(w3 + o * 400 + h * 200);
        const float4* av = (const float4*)(s_a2 + h * 200);
        float m = -1e30f;
        #pragma unroll 5
        for (int l = 0; l < 50; ++l) {
            const float4 w = wv[l];
            const float4 a = av[l];
            m = fmaxf(m, fmaxf(fmaxf(a.x + w.x, a.y + w.y),
                               fmaxf(a.z + w.z, a.w + w.w)));
        }
        m = fmaxf(m, __shfl_xor(m, 1));
        if (h == 0) s_a3[o] = fmaxf(m - 1.0f, 0.0f);
    }
    __syncthreads();

    if (tid < 84) {
        float acc = 0.0f;
        for (int i = 0; i < 120; ++i)
            acc = fmaf(s_a3[i], wd[i * 84 + tid], acc);
        s_a4[tid] = tanhf(acc);
    }
    __syncthreads();

    if (tid < 10) {
        float acc = bfv[tid];
        for (int i = 0; i < 84; ++i)
            acc = fmaf(s_a4[i], wf[i * 10 + tid], acc);
        s_logits[tid] = acc;
    }
    __syncthreads();

    if (tid == 0) {
        float m = s_logits[0];
        for (int i = 1; i < 10; ++i) m = fmaxf(m, s_logits[i]);
        float s = 0.0f;
        for (int i = 0; i < 10; ++i) s += expf(s_logits[i] - m);
        s_red[0] = m;
        s_red[1] = logf(s);
    }
    __syncthreads();
    if (tid < 10)
        out[img * 10 + tid] = s_logits[tid] - s_red[0] - s_red[1];
}

extern "C" void kernel_launch(void* const* d_in, const int* in_sizes, int n_in,
                              void* d_out, int out_size, void* d_ws, size_t ws_size,
                              hipStream_t stream) {
    const float* x   = (const float*)d_in[0];
    const float* w1  = (const float*)d_in[1];
    const float* w2  = (const float*)d_in[2];
    const float* w3  = (const float*)d_in[3];
    const float* wd  = (const float*)d_in[4];
    const float* wf  = (const float*)d_in[5];
    const float* bfv = (const float*)d_in[6];
    float* out = (float*)d_out;

    const int B = in_sizes[0] / (3 * 32 * 32);
    float* a1 = (float*)d_ws;             // [B,6,14,14]
    float* a2 = a1 + (size_t)B * 1176;    // [B,16,5,5]

    k1_conv1<<<dim3(B * 6), dim3(256), 0, stream>>>(x, w1, a1);
    k2_conv2<<<dim3(B * 4), dim3(128), 0, stream>>>(a1, w2, a2);
    k3_head <<<dim3(B),     dim3(256), 0, stream>>>(a2, w3, wd, wf, bfv, out);
}